// Round 1
// baseline (1840.623 us; speedup 1.0000x reference)
//
#include <hip/hip_runtime.h>

#define ALPHA 0.2f
#define EPSV 1e-8f

// ---------------------------------------------------------------------------
// GEMM: h[r] = X @ Wr[r] * ee[r]   (r = 0 pos, 1 neg), X: N x 256, Wr[r]: 256 x 128
// block = 256 threads, tile = 64 rows x 128 cols, both relations per block.
// ---------------------------------------------------------------------------
__global__ __launch_bounds__(256) void gemm_kernel(
    const float* __restrict__ X,
    const float* __restrict__ Wr,
    const float* __restrict__ ee,
    float* __restrict__ h,
    int N)
{
    __shared__ float As[64][33];        // padded: conflict-free column reads
    __shared__ float Bs[2][32][128];
    const int tid = threadIdx.x;
    const int row0 = blockIdx.x * 64;
    const int tx = tid & 15;            // col group: cols tx + 16*j
    const int ty = tid >> 4;            // row group: rows ty*4 + i

    float acc[2][4][8];
    #pragma unroll
    for (int r = 0; r < 2; ++r)
        #pragma unroll
        for (int i = 0; i < 4; ++i)
            #pragma unroll
            for (int j = 0; j < 8; ++j) acc[r][i][j] = 0.f;

    for (int k0 = 0; k0 < 256; k0 += 32) {
        // stage A: 64 rows x 32 k
        {
            const int ar = tid >> 3;
            const int ak = (tid & 7) * 4;
            #pragma unroll
            for (int p = 0; p < 2; ++p) {
                const int r = row0 + ar + p * 32;
                float4 v = make_float4(0.f, 0.f, 0.f, 0.f);
                if (r < N)
                    v = *reinterpret_cast<const float4*>(&X[(size_t)r * 256 + k0 + ak]);
                As[ar + p * 32][ak + 0] = v.x;
                As[ar + p * 32][ak + 1] = v.y;
                As[ar + p * 32][ak + 2] = v.z;
                As[ar + p * 32][ak + 3] = v.w;
            }
        }
        // stage B for both relations: 32 k x 128 cols each
        {
            const int bk = tid >> 5;            // 0..7
            const int bc = (tid & 31) * 4;      // 0..124
            #pragma unroll
            for (int r = 0; r < 2; ++r)
                #pragma unroll
                for (int p = 0; p < 4; ++p) {
                    const int kk = bk + p * 8;
                    *reinterpret_cast<float4*>(&Bs[r][kk][bc]) =
                        *reinterpret_cast<const float4*>(
                            &Wr[(size_t)r * 256 * 128 + (size_t)(k0 + kk) * 128 + bc]);
                }
        }
        __syncthreads();
        #pragma unroll
        for (int kk = 0; kk < 32; ++kk) {
            float a[4], b0[8], b1[8];
            #pragma unroll
            for (int i = 0; i < 4; ++i) a[i] = As[ty * 4 + i][kk];
            #pragma unroll
            for (int j = 0; j < 8; ++j) {
                b0[j] = Bs[0][kk][tx + 16 * j];
                b1[j] = Bs[1][kk][tx + 16 * j];
            }
            #pragma unroll
            for (int i = 0; i < 4; ++i)
                #pragma unroll
                for (int j = 0; j < 8; ++j) {
                    acc[0][i][j] += a[i] * b0[j];
                    acc[1][i][j] += a[i] * b1[j];
                }
        }
        __syncthreads();
    }
    // epilogue: scale by edge_embedding[r][col], store
    #pragma unroll
    for (int r = 0; r < 2; ++r)
        #pragma unroll
        for (int i = 0; i < 4; ++i) {
            const int row = row0 + ty * 4 + i;
            if (row >= N) continue;
            #pragma unroll
            for (int j = 0; j < 8; ++j) {
                const int col = tx + 16 * j;
                h[(size_t)r * N * 128 + (size_t)row * 128 + col] =
                    acc[r][i][j] * ee[r * 128 + col];
            }
        }
}

// ---------------------------------------------------------------------------
// s/d per node: s = h . a_src, d = h . a_dst  for both relations.
// One wave per node.
// ---------------------------------------------------------------------------
__global__ __launch_bounds__(256) void sd_kernel(
    const float* __restrict__ h,
    const float* __restrict__ a,
    float* __restrict__ sd,       // [s_pos | d_pos | s_neg | d_neg], each N
    int N)
{
    const long long gw = ((long long)blockIdx.x * blockDim.x + threadIdx.x) >> 6;
    const int lane = threadIdx.x & 63;
    if (gw >= N) return;
    const int n = (int)gw;

    const float2 hp = *reinterpret_cast<const float2*>(&h[(size_t)n * 128 + lane * 2]);
    const float2 hn = *reinterpret_cast<const float2*>(
        &h[(size_t)N * 128 + (size_t)n * 128 + lane * 2]);
    const float2 as = *reinterpret_cast<const float2*>(&a[lane * 2]);
    const float2 ad = *reinterpret_cast<const float2*>(&a[128 + lane * 2]);

    float sp = hp.x * as.x + hp.y * as.y;
    float dp = hp.x * ad.x + hp.y * ad.y;
    float sn = hn.x * as.x + hn.y * as.y;
    float dn = hn.x * ad.x + hn.y * ad.y;

    #pragma unroll
    for (int off = 32; off >= 1; off >>= 1) {
        sp += __shfl_xor(sp, off);
        dp += __shfl_xor(dp, off);
        sn += __shfl_xor(sn, off);
        dn += __shfl_xor(dn, off);
    }
    if (lane == 0) {
        sd[n]         = sp;
        sd[N + n]     = dp;
        sd[2 * N + n] = sn;
        sd[3 * N + n] = dn;
    }
}

// ---------------------------------------------------------------------------
// Edge phase: one wave per edge. e = sigmoid(leakyrelu(s[src] + d[dst])),
// atomically accumulate e * h[dst] into out[src], e into row_sum[src].
// ---------------------------------------------------------------------------
__global__ __launch_bounds__(256) void edge_kernel(
    const int* __restrict__ adj_pos,
    const int* __restrict__ adj_neg,
    const float* __restrict__ h,
    const float* __restrict__ sd,
    float* __restrict__ out,
    float* __restrict__ row_sum,
    int N, int E)
{
    const long long gw = ((long long)blockIdx.x * blockDim.x + threadIdx.x) >> 6;
    const int lane = threadIdx.x & 63;
    if (gw >= 2LL * E) return;
    const int rel = gw >= E;
    const int eidx = (int)(rel ? gw - E : gw);
    const int* __restrict__ adj = rel ? adj_neg : adj_pos;
    const int src = adj[eidx];
    const int dst = adj[E + eidx];

    const float* s = sd + (size_t)rel * 2 * N;
    const float* d = s + N;
    float z = s[src] + d[dst];
    z = z > 0.f ? z : ALPHA * z;
    const float e = 1.f / (1.f + __expf(-z));

    const float* hrow = h + (size_t)rel * N * 128 + (size_t)dst * 128;
    const float2 hv = *reinterpret_cast<const float2*>(&hrow[lane * 2]);
    float* orow = out + (size_t)src * 128;
    atomicAdd(&orow[lane * 2 + 0], e * hv.x);
    atomicAdd(&orow[lane * 2 + 1], e * hv.y);
    if (lane == 0) atomicAdd(&row_sum[src], e);
}

// ---------------------------------------------------------------------------
// Finalize: out = out / (row_sum + EPS) + bias
// ---------------------------------------------------------------------------
__global__ __launch_bounds__(256) void finalize_kernel(
    float* __restrict__ out,
    const float* __restrict__ row_sum,
    const float* __restrict__ bias,
    int N)
{
    const long long i = (long long)blockIdx.x * blockDim.x + threadIdx.x;
    if (i >= (long long)N * 128) return;
    const int n = (int)(i >> 7);
    const int c = (int)(i & 127);
    out[i] = out[i] / (row_sum[n] + EPSV) + bias[c];
}

extern "C" void kernel_launch(void* const* d_in, const int* in_sizes, int n_in,
                              void* d_out, int out_size, void* d_ws, size_t ws_size,
                              hipStream_t stream) {
    const float* X      = (const float*)d_in[0];   // N x 256
    const float* ee     = (const float*)d_in[1];   // 2 x 128
    const float* Wr     = (const float*)d_in[2];   // 2 x 256 x 128
    const float* a      = (const float*)d_in[3];   // 1 x 256
    const float* bias   = (const float*)d_in[4];   // 1 x 128
    const int* adj_pos  = (const int*)d_in[5];     // 2 x E
    const int* adj_neg  = (const int*)d_in[6];     // 2 x E

    const int N = in_sizes[0] / 256;
    const int E = in_sizes[5] / 2;
    float* out = (float*)d_out;

    char* ws = (char*)d_ws;
    float* h       = (float*)ws;                                  // 2*N*128 f32
    float* sd      = (float*)(ws + (size_t)2 * N * 128 * 4);      // 4*N f32
    float* row_sum = sd + 4 * (size_t)N;                          // N f32

    hipMemsetAsync(out, 0, (size_t)N * 128 * sizeof(float), stream);
    hipMemsetAsync(row_sum, 0, (size_t)N * sizeof(float), stream);

    gemm_kernel<<<(N + 63) / 64, 256, 0, stream>>>(X, Wr, ee, h, N);
    sd_kernel<<<(N + 3) / 4, 256, 0, stream>>>(h, a, sd, N);

    const long long waves = 2LL * E;
    edge_kernel<<<(int)((waves + 3) / 4), 256, 0, stream>>>(
        adj_pos, adj_neg, h, sd, out, row_sum, N, E);

    finalize_kernel<<<(int)(((long long)N * 128 + 255) / 256), 256, 0, stream>>>(
        out, row_sum, bias, N);
}

// Round 2
// 782.487 us; speedup vs baseline: 2.3523x; 2.3523x over previous
//
#include <hip/hip_runtime.h>

#define ALPHA 0.2f
#define EPSV 1e-8f
#define SCAN_CHUNK 2048   // elements per scan1 block (256 thr x 8)

// ---------------------------------------------------------------------------
// GEMM: h[r] = X @ Wr[r] * ee[r]  (r=0 pos, 1 neg) + fused s/d epilogue:
//   sd[r*2N + n]     = h[r][n] . a[0:128]    (s)
//   sd[r*2N + N + n] = h[r][n] . a[128:256]  (d)
// block = 256 threads, tile = 64 rows x 128 cols, both relations per block.
// ---------------------------------------------------------------------------
__global__ __launch_bounds__(256) void gemm_kernel(
    const float* __restrict__ X,
    const float* __restrict__ Wr,
    const float* __restrict__ ee,
    const float* __restrict__ a,
    float* __restrict__ h,
    float* __restrict__ sd,
    int N)
{
    __shared__ float As[64][33];
    __shared__ float Bs[2][32][128];
    const int tid = threadIdx.x;
    const int row0 = blockIdx.x * 64;
    const int tx = tid & 15;            // col group: cols tx + 16*j
    const int ty = tid >> 4;            // row group: rows ty*4 + i

    float acc[2][4][8];
    #pragma unroll
    for (int r = 0; r < 2; ++r)
        #pragma unroll
        for (int i = 0; i < 4; ++i)
            #pragma unroll
            for (int j = 0; j < 8; ++j) acc[r][i][j] = 0.f;

    for (int k0 = 0; k0 < 256; k0 += 32) {
        {
            const int ar = tid >> 3;
            const int ak = (tid & 7) * 4;
            #pragma unroll
            for (int p = 0; p < 2; ++p) {
                const int r = row0 + ar + p * 32;
                float4 v = make_float4(0.f, 0.f, 0.f, 0.f);
                if (r < N)
                    v = *reinterpret_cast<const float4*>(&X[(size_t)r * 256 + k0 + ak]);
                As[ar + p * 32][ak + 0] = v.x;
                As[ar + p * 32][ak + 1] = v.y;
                As[ar + p * 32][ak + 2] = v.z;
                As[ar + p * 32][ak + 3] = v.w;
            }
        }
        {
            const int bk = tid >> 5;
            const int bc = (tid & 31) * 4;
            #pragma unroll
            for (int r = 0; r < 2; ++r)
                #pragma unroll
                for (int p = 0; p < 4; ++p) {
                    const int kk = bk + p * 8;
                    *reinterpret_cast<float4*>(&Bs[r][kk][bc]) =
                        *reinterpret_cast<const float4*>(
                            &Wr[(size_t)r * 256 * 128 + (size_t)(k0 + kk) * 128 + bc]);
                }
        }
        __syncthreads();
        #pragma unroll
        for (int kk = 0; kk < 32; ++kk) {
            float av[4], b0[8], b1[8];
            #pragma unroll
            for (int i = 0; i < 4; ++i) av[i] = As[ty * 4 + i][kk];
            #pragma unroll
            for (int j = 0; j < 8; ++j) {
                b0[j] = Bs[0][kk][tx + 16 * j];
                b1[j] = Bs[1][kk][tx + 16 * j];
            }
            #pragma unroll
            for (int i = 0; i < 4; ++i)
                #pragma unroll
                for (int j = 0; j < 8; ++j) {
                    acc[0][i][j] += av[i] * b0[j];
                    acc[1][i][j] += av[i] * b1[j];
                }
        }
        __syncthreads();
    }

    // epilogue: scale by ee, store h, fused s/d dot products
    float eev[2][8], asv[8], adv[8];
    #pragma unroll
    for (int j = 0; j < 8; ++j) {
        const int col = tx + 16 * j;
        eev[0][j] = ee[col];
        eev[1][j] = ee[128 + col];
        asv[j] = a[col];
        adv[j] = a[128 + col];
    }
    #pragma unroll
    for (int r = 0; r < 2; ++r) {
        #pragma unroll
        for (int i = 0; i < 4; ++i) {
            const int row = row0 + ty * 4 + i;
            float sp = 0.f, dp = 0.f;
            #pragma unroll
            for (int j = 0; j < 8; ++j) {
                const float v = acc[r][i][j] * eev[r][j];
                sp += v * asv[j];
                dp += v * adv[j];
                if (row < N)
                    h[(size_t)r * N * 128 + (size_t)row * 128 + tx + 16 * j] = v;
            }
            // reduce over the 16 tx lanes (same ty) within the wave
            #pragma unroll
            for (int off = 1; off < 16; off <<= 1) {
                sp += __shfl_xor(sp, off);
                dp += __shfl_xor(dp, off);
            }
            if (tx == 0 && row < N) {
                sd[(size_t)r * 2 * N + row]     = sp;
                sd[(size_t)r * 2 * N + N + row] = dp;
            }
        }
    }
}

// ---------------------------------------------------------------------------
// CSR build
// ---------------------------------------------------------------------------
__global__ __launch_bounds__(256) void count_kernel(
    const int* __restrict__ adj_pos, const int* __restrict__ adj_neg,
    int* __restrict__ deg, int E)
{
    const int idx = blockIdx.x * blockDim.x + threadIdx.x;
    if (idx >= 2 * E) return;
    const int src = (idx < E) ? adj_pos[idx] : adj_neg[idx - E];
    atomicAdd(&deg[src], 1);
}

// scan1: per-block exclusive scan of SCAN_CHUNK elements, in place; blockSums out
__global__ __launch_bounds__(256) void scan1_kernel(
    int* __restrict__ deg, int* __restrict__ blockSums, int N)
{
    __shared__ int s[256];
    const int t = threadIdx.x;
    const int base = blockIdx.x * SCAN_CHUNK + t * 8;
    int local[8];
    int sum = 0;
    #pragma unroll
    for (int k = 0; k < 8; ++k) {
        const int i = base + k;
        const int v = (i < N) ? deg[i] : 0;
        local[k] = sum;
        sum += v;
    }
    s[t] = sum;
    __syncthreads();
    int incl = sum;
    for (int off = 1; off < 256; off <<= 1) {
        const int u = (t >= off) ? s[t - off] : 0;
        __syncthreads();
        incl += u;
        s[t] = incl;
        __syncthreads();
    }
    const int texcl = incl - sum;
    #pragma unroll
    for (int k = 0; k < 8; ++k) {
        const int i = base + k;
        if (i < N) deg[i] = texcl + local[k];
    }
    if (t == 255) blockSums[blockIdx.x] = incl;
}

// scan2: single-block exclusive scan of blockSums (nb <= 256)
__global__ __launch_bounds__(256) void scan2_kernel(int* __restrict__ blockSums, int nb)
{
    __shared__ int s[256];
    const int t = threadIdx.x;
    const int v = (t < nb) ? blockSums[t] : 0;
    s[t] = v;
    __syncthreads();
    int incl = v;
    for (int off = 1; off < 256; off <<= 1) {
        const int u = (t >= off) ? s[t - off] : 0;
        __syncthreads();
        incl += u;
        s[t] = incl;
        __syncthreads();
    }
    if (t < nb) blockSums[t] = incl - v;
}

// scan3: rowPtr[i] = deg[i] + blockSums[i/SCAN_CHUNK]; cursor copy; rowPtr[N]=2E
__global__ __launch_bounds__(256) void scan3_kernel(
    const int* __restrict__ deg, const int* __restrict__ blockSums,
    int* __restrict__ rowPtr, int* __restrict__ cursor, int N, int twoE)
{
    const int i = blockIdx.x * blockDim.x + threadIdx.x;
    if (i == 0) rowPtr[N] = twoE;
    if (i >= N) return;
    const int v = deg[i] + blockSums[i / SCAN_CHUNK];
    rowPtr[i] = v;
    cursor[i] = v;
}

__global__ __launch_bounds__(256) void fill_kernel(
    const int* __restrict__ adj_pos, const int* __restrict__ adj_neg,
    int* __restrict__ cursor, int* __restrict__ edges, int E)
{
    const int idx = blockIdx.x * blockDim.x + threadIdx.x;
    if (idx >= 2 * E) return;
    const int rel = (idx >= E) ? 1 : 0;
    const int e = rel ? idx - E : idx;
    const int* __restrict__ adj = rel ? adj_neg : adj_pos;
    const int src = adj[e];
    const int dst = adj[E + e];
    const int pos = atomicAdd(&cursor[src], 1);
    edges[pos] = dst | (rel << 30);
}

// ---------------------------------------------------------------------------
// Gather: one wave per node. Walk CSR bucket, recompute e, accumulate e*h[dst]
// in registers, write out = acc/(sum_e+EPS) + bias.  No atomics.
// ---------------------------------------------------------------------------
__global__ __launch_bounds__(256) void gather_kernel(
    const int* __restrict__ rowPtr, const int* __restrict__ edges,
    const float* __restrict__ h, const float* __restrict__ sd,
    const float* __restrict__ bias, float* __restrict__ out, int N)
{
    const long long gw = ((long long)blockIdx.x * blockDim.x + threadIdx.x) >> 6;
    const int lane = threadIdx.x & 63;
    if (gw >= N) return;
    const int n = (int)gw;

    const int beg = rowPtr[n];
    const int end = rowPtr[n + 1];
    const float s0 = sd[n];
    const float s1 = sd[2 * (size_t)N + n];
    const float* __restrict__ d0 = sd + N;
    const float* __restrict__ d1 = sd + 3 * (size_t)N;

    float ax = 0.f, ay = 0.f, rs = 0.f;
    for (int j = beg; j < end; ++j) {
        const int ed = edges[j];
        const int rel = ed >> 30;
        const int dst = ed & 0x3FFFFFFF;
        float z = rel ? (s1 + d1[dst]) : (s0 + d0[dst]);
        z = z > 0.f ? z : ALPHA * z;
        const float e = 1.f / (1.f + __expf(-z));
        const float* hrow = h + (size_t)rel * N * 128 + (size_t)dst * 128;
        const float2 hv = *reinterpret_cast<const float2*>(&hrow[lane * 2]);
        ax += e * hv.x;
        ay += e * hv.y;
        rs += e;
    }
    const float inv = 1.f / (rs + EPSV);
    const float2 bv = *reinterpret_cast<const float2*>(&bias[lane * 2]);
    float2 o;
    o.x = ax * inv + bv.x;
    o.y = ay * inv + bv.y;
    *reinterpret_cast<float2*>(&out[(size_t)n * 128 + lane * 2]) = o;
}

extern "C" void kernel_launch(void* const* d_in, const int* in_sizes, int n_in,
                              void* d_out, int out_size, void* d_ws, size_t ws_size,
                              hipStream_t stream) {
    const float* X      = (const float*)d_in[0];   // N x 256
    const float* ee     = (const float*)d_in[1];   // 2 x 128
    const float* Wr     = (const float*)d_in[2];   // 2 x 256 x 128
    const float* a      = (const float*)d_in[3];   // 1 x 256
    const float* bias   = (const float*)d_in[4];   // 1 x 128
    const int* adj_pos  = (const int*)d_in[5];     // 2 x E
    const int* adj_neg  = (const int*)d_in[6];     // 2 x E

    const int N = in_sizes[0] / 256;
    const int E = in_sizes[5] / 2;
    const int twoE = 2 * E;
    float* out = (float*)d_out;

    // workspace layout
    char* ws = (char*)d_ws;
    float* h       = (float*)ws;                          // 2*N*128 f32 = 102.4 MB
    char* p = ws + (size_t)2 * N * 128 * 4;
    float* sd      = (float*)p;  p += (size_t)4 * N * 4;  // 4N f32
    int* deg       = (int*)p;    p += (size_t)N * 4;      // N (scanned in place)
    int* rowPtr    = (int*)p;    p += (size_t)(N + 1) * 4;
    int* cursor    = (int*)p;    p += (size_t)N * 4;
    int* blockSums = (int*)p;    p += 256 * 4;
    int* edges     = (int*)p;    p += (size_t)twoE * 4;   // 6.4 MB

    const int nb = (N + SCAN_CHUNK - 1) / SCAN_CHUNK;

    hipMemsetAsync(deg, 0, (size_t)N * sizeof(int), stream);

    gemm_kernel<<<(N + 63) / 64, 256, 0, stream>>>(X, Wr, ee, a, h, sd, N);

    count_kernel<<<(twoE + 255) / 256, 256, 0, stream>>>(adj_pos, adj_neg, deg, E);
    scan1_kernel<<<nb, 256, 0, stream>>>(deg, blockSums, N);
    scan2_kernel<<<1, 256, 0, stream>>>(blockSums, nb);
    scan3_kernel<<<(N + 255) / 256, 256, 0, stream>>>(deg, blockSums, rowPtr, cursor, N, twoE);
    fill_kernel<<<(twoE + 255) / 256, 256, 0, stream>>>(adj_pos, adj_neg, cursor, edges, E);

    gather_kernel<<<(int)(((long long)N * 64 + 255) / 256), 256, 0, stream>>>(
        rowPtr, edges, h, sd, bias, out, N);
}

// Round 4
// 446.525 us; speedup vs baseline: 4.1221x; 1.7524x over previous
//
#include <hip/hip_runtime.h>

#define ALPHA 0.2f
#define EPSV 1e-8f
#define SCAN_CHUNK 2048

typedef float f32x4 __attribute__((ext_vector_type(4)));
typedef short bf16x8 __attribute__((ext_vector_type(8)));

static __device__ __forceinline__ unsigned short f2bf(float f) {
    union { float f; unsigned int u; } c; c.f = f;
    unsigned int u = c.u;
    unsigned int round = ((u >> 16) & 1) + 0x7FFF;
    return (unsigned short)((u + round) >> 16);
}

// ---------------------------------------------------------------------------
// convA: X (N x 256 f32) -> Ap packed bf16 MFMA-A layout.
// Ap 16B-unit index: (rt*32 + kb)*16 + i   holds X[rt*16+i][kb*8 .. kb*8+7]
// ---------------------------------------------------------------------------
__global__ __launch_bounds__(256) void convA_kernel(
    const float* __restrict__ X, uint4* __restrict__ Ap, int N, int Mpad)
{
    const int t = blockIdx.x * blockDim.x + threadIdx.x;
    if (t >= Mpad * 32) return;
    const int rt = t >> 9;
    const int kb = (t >> 4) & 31;
    const int i  = t & 15;
    const int r  = rt * 16 + i;
    unsigned short v[8];
    if (r < N) {
        const float4 f0 = *reinterpret_cast<const float4*>(&X[(size_t)r * 256 + kb * 8]);
        const float4 f1 = *reinterpret_cast<const float4*>(&X[(size_t)r * 256 + kb * 8 + 4]);
        v[0]=f2bf(f0.x); v[1]=f2bf(f0.y); v[2]=f2bf(f0.z); v[3]=f2bf(f0.w);
        v[4]=f2bf(f1.x); v[5]=f2bf(f1.y); v[6]=f2bf(f1.z); v[7]=f2bf(f1.w);
    } else {
        #pragma unroll
        for (int k = 0; k < 8; ++k) v[k] = 0;
    }
    Ap[t] = *reinterpret_cast<const uint4*>(v);
}

// ---------------------------------------------------------------------------
// convB: Wr (2 x 256 x 128 f32) -> Bp packed bf16 MFMA-B layout.
// Bp 16B-unit index: kb*256 + col  holds B[kb*8 .. kb*8+7][col]
// where B[k][col] = Wr[col>>7][k][col&127].
// ---------------------------------------------------------------------------
__global__ __launch_bounds__(256) void convB_kernel(
    const float* __restrict__ Wr, uint4* __restrict__ Bp)
{
    const int t = blockIdx.x * blockDim.x + threadIdx.x;
    if (t >= 32 * 256) return;
    const int kb  = t >> 8;
    const int col = t & 255;
    const int rel = col >> 7;
    const int cc  = col & 127;
    unsigned short v[8];
    #pragma unroll
    for (int jj = 0; jj < 8; ++jj) {
        const int k = kb * 8 + jj;
        v[jj] = f2bf(Wr[(size_t)rel * 256 * 128 + (size_t)k * 128 + cc]);
    }
    Bp[t] = *reinterpret_cast<const uint4*>(v);
}

// ---------------------------------------------------------------------------
// MFMA GEMM: C = A(Mpad x 256) * B(256 x 256), scaled by ee -> h (bf16 u16),
// fused s/d epilogue -> sd.
// Block = 256 thr = 4 waves (2 M x 2 N). Wave: 32 rows x 128 cols.
// No LDS, no barriers: A coalesced from HBM, B broadcast from L2.
// ---------------------------------------------------------------------------
__global__ __launch_bounds__(256) void mfma_gemm_kernel(
    const uint4* __restrict__ Ap, const uint4* __restrict__ Bp,
    const float* __restrict__ ee, const float* __restrict__ a,
    unsigned short* __restrict__ h, float* __restrict__ sd, int N)
{
    const int tid  = threadIdx.x;
    const int lane = tid & 63;
    const int w    = tid >> 6;
    const int wm   = w >> 1;
    const int wn   = w & 1;
    const int rtb  = blockIdx.x * 4 + wm * 2;   // first of 2 row-tiles of 16
    const int cl   = lane & 15;
    const int g    = lane >> 4;

    f32x4 acc[2][8];
    #pragma unroll
    for (int p = 0; p < 2; ++p)
        #pragma unroll
        for (int ct = 0; ct < 8; ++ct)
            acc[p][ct] = (f32x4){0.f, 0.f, 0.f, 0.f};

    #pragma unroll
    for (int kc = 0; kc < 8; ++kc) {
        bf16x8 af[2], bf[8];
        #pragma unroll
        for (int p = 0; p < 2; ++p)
            af[p] = *reinterpret_cast<const bf16x8*>(
                Ap + ((size_t)(rtb + p) * 32 + kc * 4) * 16 + lane);
        #pragma unroll
        for (int ct = 0; ct < 8; ++ct) {
            const int kb  = kc * 4 + g;
            const int col = wn * 128 + ct * 16 + cl;
            bf[ct] = *reinterpret_cast<const bf16x8*>(Bp + kb * 256 + col);
        }
        #pragma unroll
        for (int p = 0; p < 2; ++p)
            #pragma unroll
            for (int ct = 0; ct < 8; ++ct)
                acc[p][ct] = __builtin_amdgcn_mfma_f32_16x16x32_bf16(
                    af[p], bf[ct], acc[p][ct], 0, 0, 0);
    }

    // epilogue: scale by ee, store h (bf16), fused s/d dots for relation wn
    float eev[8], asv[8], adv[8];
    #pragma unroll
    for (int ct = 0; ct < 8; ++ct) {
        const int col = wn * 128 + ct * 16 + cl;
        const int cc  = col & 127;
        eev[ct] = ee[col];
        asv[ct] = a[cc];
        adv[ct] = a[128 + cc];
    }

    float s_acc[2][4], d_acc[2][4];
    #pragma unroll
    for (int p = 0; p < 2; ++p) {
        #pragma unroll
        for (int reg = 0; reg < 4; ++reg) {
            const int row = (rtb + p) * 16 + g * 4 + reg;
            const bool ok = row < N;
            float sp = 0.f, dp = 0.f;
            #pragma unroll
            for (int ct = 0; ct < 8; ++ct) {
                const float v = acc[p][ct][reg] * eev[ct];
                sp += v * asv[ct];
                dp += v * adv[ct];
                if (ok) {
                    const int cc = ct * 16 + cl;
                    h[((size_t)wn * N + row) * 128 + cc] = f2bf(v);
                }
            }
            s_acc[p][reg] = sp;
            d_acc[p][reg] = dp;
        }
    }
    // reduce over the 16 cl lanes within each lane-group
    #pragma unroll
    for (int p = 0; p < 2; ++p)
        #pragma unroll
        for (int reg = 0; reg < 4; ++reg) {
            float sp = s_acc[p][reg], dp = d_acc[p][reg];
            #pragma unroll
            for (int off = 1; off < 16; off <<= 1) {
                sp += __shfl_xor(sp, off);
                dp += __shfl_xor(dp, off);
            }
            if (cl == 0) {
                const int row = (rtb + p) * 16 + g * 4 + reg;
                if (row < N) {
                    sd[(size_t)wn * 2 * N + row]     = sp;
                    sd[(size_t)wn * 2 * N + N + row] = dp;
                }
            }
        }
}

// ---------------------------------------------------------------------------
// CSR build
// ---------------------------------------------------------------------------
__global__ __launch_bounds__(256) void count_kernel(
    const int* __restrict__ adj_pos, const int* __restrict__ adj_neg,
    int* __restrict__ deg, int E)
{
    const int idx = blockIdx.x * blockDim.x + threadIdx.x;
    if (idx >= 2 * E) return;
    const int src = (idx < E) ? adj_pos[idx] : adj_neg[idx - E];
    atomicAdd(&deg[src], 1);
}

__global__ __launch_bounds__(256) void scan1_kernel(
    int* __restrict__ deg, int* __restrict__ blockSums, int N)
{
    __shared__ int s[256];
    const int t = threadIdx.x;
    const int base = blockIdx.x * SCAN_CHUNK + t * 8;
    int local[8];
    int sum = 0;
    #pragma unroll
    for (int k = 0; k < 8; ++k) {
        const int i = base + k;
        const int v = (i < N) ? deg[i] : 0;
        local[k] = sum;
        sum += v;
    }
    s[t] = sum;
    __syncthreads();
    int incl = sum;
    for (int off = 1; off < 256; off <<= 1) {
        const int u = (t >= off) ? s[t - off] : 0;
        __syncthreads();
        incl += u;
        s[t] = incl;
        __syncthreads();
    }
    const int texcl = incl - sum;
    #pragma unroll
    for (int k = 0; k < 8; ++k) {
        const int i = base + k;
        if (i < N) deg[i] = texcl + local[k];
    }
    if (t == 255) blockSums[blockIdx.x] = incl;
}

__global__ __launch_bounds__(256) void scan2_kernel(int* __restrict__ blockSums, int nb)
{
    __shared__ int s[256];
    const int t = threadIdx.x;
    const int v = (t < nb) ? blockSums[t] : 0;
    s[t] = v;
    __syncthreads();
    int incl = v;
    for (int off = 1; off < 256; off <<= 1) {
        const int u = (t >= off) ? s[t - off] : 0;
        __syncthreads();
        incl += u;
        s[t] = incl;
        __syncthreads();
    }
    if (t < nb) blockSums[t] = incl - v;
}

__global__ __launch_bounds__(256) void scan3_kernel(
    const int* __restrict__ deg, const int* __restrict__ blockSums,
    int* __restrict__ rowPtr, int* __restrict__ cursor, int N, int twoE)
{
    const int i = blockIdx.x * blockDim.x + threadIdx.x;
    if (i == 0) rowPtr[N] = twoE;
    if (i >= N) return;
    const int v = deg[i] + blockSums[i / SCAN_CHUNK];
    rowPtr[i] = v;
    cursor[i] = v;
}

__global__ __launch_bounds__(256) void fill_kernel(
    const int* __restrict__ adj_pos, const int* __restrict__ adj_neg,
    int* __restrict__ cursor, int* __restrict__ edges, int E)
{
    const int idx = blockIdx.x * blockDim.x + threadIdx.x;
    if (idx >= 2 * E) return;
    const int rel = (idx >= E) ? 1 : 0;
    const int e = rel ? idx - E : idx;
    const int* __restrict__ adj = rel ? adj_neg : adj_pos;
    const int src = adj[e];
    const int dst = adj[E + e];
    const int pos = atomicAdd(&cursor[src], 1);
    edges[pos] = dst | (rel << 30);
}

// ---------------------------------------------------------------------------
// Gather: one wave per node; h is bf16 (u16) now, 256B per row.
// ---------------------------------------------------------------------------
__global__ __launch_bounds__(256) void gather_kernel(
    const int* __restrict__ rowPtr, const int* __restrict__ edges,
    const unsigned short* __restrict__ h, const float* __restrict__ sd,
    const float* __restrict__ bias, float* __restrict__ out, int N)
{
    const long long gw = ((long long)blockIdx.x * blockDim.x + threadIdx.x) >> 6;
    const int lane = threadIdx.x & 63;
    if (gw >= N) return;
    const int n = (int)gw;

    const int beg = rowPtr[n];
    const int end = rowPtr[n + 1];
    const float s0 = sd[n];
    const float s1 = sd[2 * (size_t)N + n];
    const float* __restrict__ d0 = sd + N;
    const float* __restrict__ d1 = sd + 3 * (size_t)N;

    float ax = 0.f, ay = 0.f, rs = 0.f;
    for (int j = beg; j < end; ++j) {
        const int ed = edges[j];
        const int rel = ed >> 30;
        const int dst = ed & 0x3FFFFFFF;
        float z = rel ? (s1 + d1[dst]) : (s0 + d0[dst]);
        z = z > 0.f ? z : ALPHA * z;
        const float e = 1.f / (1.f + __expf(-z));
        const unsigned int hv = *reinterpret_cast<const unsigned int*>(
            &h[((size_t)rel * N + dst) * 128 + lane * 2]);
        union { unsigned int u; float f; } cx, cy;
        cx.u = hv << 16;
        cy.u = hv & 0xFFFF0000u;
        ax += e * cx.f;
        ay += e * cy.f;
        rs += e;
    }
    const float inv = 1.f / (rs + EPSV);
    const float2 bv = *reinterpret_cast<const float2*>(&bias[lane * 2]);
    float2 o;
    o.x = ax * inv + bv.x;
    o.y = ay * inv + bv.y;
    *reinterpret_cast<float2*>(&out[(size_t)n * 128 + lane * 2]) = o;
}

extern "C" void kernel_launch(void* const* d_in, const int* in_sizes, int n_in,
                              void* d_out, int out_size, void* d_ws, size_t ws_size,
                              hipStream_t stream) {
    const float* X      = (const float*)d_in[0];   // N x 256
    const float* ee     = (const float*)d_in[1];   // 2 x 128
    const float* Wr     = (const float*)d_in[2];   // 2 x 256 x 128
    const float* a      = (const float*)d_in[3];   // 1 x 256
    const float* bias   = (const float*)d_in[4];   // 1 x 128
    const int* adj_pos  = (const int*)d_in[5];     // 2 x E
    const int* adj_neg  = (const int*)d_in[6];     // 2 x E

    const int N = in_sizes[0] / 256;
    const int E = in_sizes[5] / 2;
    const int twoE = 2 * E;
    float* out = (float*)d_out;

    const int gemmBlocks = (N + 63) / 64;
    const int Mpad = gemmBlocks * 64;

    // workspace layout
    char* ws = (char*)d_ws;
    uint4* Ap = (uint4*)ws;                         // Mpad*32 uint4 = Mpad*512B
    char* p = ws + (size_t)Mpad * 512;
    uint4* Bp = (uint4*)p;       p += 32 * 256 * 16;            // 128 KB
    unsigned short* h = (unsigned short*)p; p += (size_t)2 * N * 128 * 2; // 51.2 MB
    float* sd      = (float*)p;  p += (size_t)4 * N * 4;
    int* deg       = (int*)p;    p += (size_t)N * 4;
    int* rowPtr    = (int*)p;    p += (size_t)(N + 1) * 4;
    int* cursor    = (int*)p;    p += (size_t)N * 4;
    int* blockSums = (int*)p;    p += 256 * 4;
    int* edges     = (int*)p;    p += (size_t)twoE * 4;

    const int nb = (N + SCAN_CHUNK - 1) / SCAN_CHUNK;

    (void)hipMemsetAsync(deg, 0, (size_t)N * sizeof(int), stream);

    convA_kernel<<<(Mpad * 32 + 255) / 256, 256, 0, stream>>>(X, Ap, N, Mpad);
    convB_kernel<<<(32 * 256 + 255) / 256, 256, 0, stream>>>(Wr, Bp);
    mfma_gemm_kernel<<<gemmBlocks, 256, 0, stream>>>(Ap, Bp, ee, a, h, sd, N);

    count_kernel<<<(twoE + 255) / 256, 256, 0, stream>>>(adj_pos, adj_neg, deg, E);
    scan1_kernel<<<nb, 256, 0, stream>>>(deg, blockSums, N);
    scan2_kernel<<<1, 256, 0, stream>>>(blockSums, nb);
    scan3_kernel<<<(N + 255) / 256, 256, 0, stream>>>(deg, blockSums, rowPtr, cursor, N, twoE);
    fill_kernel<<<(twoE + 255) / 256, 256, 0, stream>>>(adj_pos, adj_neg, cursor, edges, E);

    gather_kernel<<<(int)(((long long)N * 64 + 255) / 256), 256, 0, stream>>>(
        rowPtr, edges, h, sd, bias, out, N);
}

// Round 5
// 296.868 us; speedup vs baseline: 6.2001x; 1.5041x over previous
//
#include <hip/hip_runtime.h>

#define ALPHA 0.2f
#define EPSV 1e-8f
#define SCAN_CHUNK 2048

typedef float f32x4 __attribute__((ext_vector_type(4)));
typedef short bf16x8 __attribute__((ext_vector_type(8)));

static __device__ __forceinline__ unsigned short f2bf(float f) {
    union { float f; unsigned int u; } c; c.f = f;
    unsigned int u = c.u;
    unsigned int round = ((u >> 16) & 1) + 0x7FFF;
    return (unsigned short)((u + round) >> 16);
}
static __device__ __forceinline__ float bflo(unsigned int u) {
    union { unsigned int u; float f; } c; c.u = u << 16; return c.f;
}
static __device__ __forceinline__ float bfhi(unsigned int u) {
    union { unsigned int u; float f; } c; c.u = u & 0xFFFF0000u; return c.f;
}

// ---------------------------------------------------------------------------
// convB: Wr (2 x 256 x 128 f32) -> Bp packed bf16 MFMA-B layout.
// Bp 16B-unit index: kb*256 + col  holds B[kb*8 .. kb*8+7][col],
// B[k][col] = Wr[col>>7][k][col&127].
// ---------------------------------------------------------------------------
__global__ __launch_bounds__(256) void convB_kernel(
    const float* __restrict__ Wr, uint4* __restrict__ Bp)
{
    const int t = blockIdx.x * blockDim.x + threadIdx.x;
    if (t >= 32 * 256) return;
    const int kb  = t >> 8;
    const int col = t & 255;
    const int rel = col >> 7;
    const int cc  = col & 127;
    unsigned short v[8];
    #pragma unroll
    for (int jj = 0; jj < 8; ++jj) {
        const int k = kb * 8 + jj;
        v[jj] = f2bf(Wr[(size_t)rel * 256 * 128 + (size_t)k * 128 + cc]);
    }
    Bp[t] = *reinterpret_cast<const uint4*>(v);
}

// ---------------------------------------------------------------------------
// MFMA GEMM: C = X(N x 256) * B(256 x 256), scaled by ee -> h (bf16 u16),
// fused s/d epilogue -> sd. X read directly as f32, converted in-register.
// Block = 256 thr = 4 waves (2 M x 2 N). Wave: 32 rows x 128 cols.
// ---------------------------------------------------------------------------
__global__ __launch_bounds__(256) void mfma_gemm_kernel(
    const float* __restrict__ X, const uint4* __restrict__ Bp,
    const float* __restrict__ ee, const float* __restrict__ a,
    unsigned short* __restrict__ h, float* __restrict__ sd, int N)
{
    const int tid  = threadIdx.x;
    const int lane = tid & 63;
    const int w    = tid >> 6;
    const int wm   = w >> 1;
    const int wn   = w & 1;
    const int rtb  = blockIdx.x * 4 + wm * 2;   // first of 2 row-tiles of 16
    const int cl   = lane & 15;
    const int g    = lane >> 4;

    f32x4 acc[2][8];
    #pragma unroll
    for (int p = 0; p < 2; ++p)
        #pragma unroll
        for (int ct = 0; ct < 8; ++ct)
            acc[p][ct] = (f32x4){0.f, 0.f, 0.f, 0.f};

    const int row0 = rtb * 16 + cl;          // p=0 row
    const int row1 = row0 + 16;              // p=1 row

    #pragma unroll
    for (int kc = 0; kc < 8; ++kc) {
        bf16x8 af[2], bfr[8];
        #pragma unroll
        for (int p = 0; p < 2; ++p) {
            const int row = p ? row1 : row0;
            float4 f0 = make_float4(0.f, 0.f, 0.f, 0.f);
            float4 f1 = make_float4(0.f, 0.f, 0.f, 0.f);
            if (row < N) {
                const float* xp = &X[(size_t)row * 256 + kc * 32 + g * 8];
                f0 = *reinterpret_cast<const float4*>(xp);
                f1 = *reinterpret_cast<const float4*>(xp + 4);
            }
            unsigned short v[8];
            v[0]=f2bf(f0.x); v[1]=f2bf(f0.y); v[2]=f2bf(f0.z); v[3]=f2bf(f0.w);
            v[4]=f2bf(f1.x); v[5]=f2bf(f1.y); v[6]=f2bf(f1.z); v[7]=f2bf(f1.w);
            af[p] = *reinterpret_cast<const bf16x8*>(v);
        }
        #pragma unroll
        for (int ct = 0; ct < 8; ++ct) {
            const int kb  = kc * 4 + g;
            const int col = wn * 128 + ct * 16 + cl;
            bfr[ct] = *reinterpret_cast<const bf16x8*>(Bp + kb * 256 + col);
        }
        #pragma unroll
        for (int p = 0; p < 2; ++p)
            #pragma unroll
            for (int ct = 0; ct < 8; ++ct)
                acc[p][ct] = __builtin_amdgcn_mfma_f32_16x16x32_bf16(
                    af[p], bfr[ct], acc[p][ct], 0, 0, 0);
    }

    // epilogue: scale by ee, store h (bf16), fused s/d dots for relation wn
    float eev[8], asv[8], adv[8];
    #pragma unroll
    for (int ct = 0; ct < 8; ++ct) {
        const int col = wn * 128 + ct * 16 + cl;
        const int cc  = col & 127;
        eev[ct] = ee[col];
        asv[ct] = a[cc];
        adv[ct] = a[128 + cc];
    }

    float s_acc[2][4], d_acc[2][4];
    #pragma unroll
    for (int p = 0; p < 2; ++p) {
        #pragma unroll
        for (int reg = 0; reg < 4; ++reg) {
            const int row = (rtb + p) * 16 + g * 4 + reg;
            const bool ok = row < N;
            float sp = 0.f, dp = 0.f;
            #pragma unroll
            for (int ct = 0; ct < 8; ++ct) {
                const float v = acc[p][ct][reg] * eev[ct];
                sp += v * asv[ct];
                dp += v * adv[ct];
                if (ok) {
                    const int cc = ct * 16 + cl;
                    h[((size_t)wn * N + row) * 128 + cc] = f2bf(v);
                }
            }
            s_acc[p][reg] = sp;
            d_acc[p][reg] = dp;
        }
    }
    #pragma unroll
    for (int p = 0; p < 2; ++p)
        #pragma unroll
        for (int reg = 0; reg < 4; ++reg) {
            float sp = s_acc[p][reg], dp = d_acc[p][reg];
            #pragma unroll
            for (int off = 1; off < 16; off <<= 1) {
                sp += __shfl_xor(sp, off);
                dp += __shfl_xor(dp, off);
            }
            if (cl == 0) {
                const int row = (rtb + p) * 16 + g * 4 + reg;
                if (row < N) {
                    sd[(size_t)wn * 2 * N + row]     = sp;
                    sd[(size_t)wn * 2 * N + N + row] = dp;
                }
            }
        }
}

// ---------------------------------------------------------------------------
// CSR build
// ---------------------------------------------------------------------------
__global__ __launch_bounds__(256) void count_kernel(
    const int* __restrict__ adj_pos, const int* __restrict__ adj_neg,
    int* __restrict__ deg, int E)
{
    const int idx = blockIdx.x * blockDim.x + threadIdx.x;
    if (idx >= 2 * E) return;
    const int src = (idx < E) ? adj_pos[idx] : adj_neg[idx - E];
    atomicAdd(&deg[src], 1);
}

__global__ __launch_bounds__(256) void scan1_kernel(
    int* __restrict__ deg, int* __restrict__ blockSums, int N)
{
    __shared__ int s[256];
    const int t = threadIdx.x;
    const int base = blockIdx.x * SCAN_CHUNK + t * 8;
    int local[8];
    int sum = 0;
    #pragma unroll
    for (int k = 0; k < 8; ++k) {
        const int i = base + k;
        const int v = (i < N) ? deg[i] : 0;
        local[k] = sum;
        sum += v;
    }
    s[t] = sum;
    __syncthreads();
    int incl = sum;
    for (int off = 1; off < 256; off <<= 1) {
        const int u = (t >= off) ? s[t - off] : 0;
        __syncthreads();
        incl += u;
        s[t] = incl;
        __syncthreads();
    }
    const int texcl = incl - sum;
    #pragma unroll
    for (int k = 0; k < 8; ++k) {
        const int i = base + k;
        if (i < N) deg[i] = texcl + local[k];
    }
    if (t == 255) blockSums[blockIdx.x] = incl;
}

__global__ __launch_bounds__(256) void scan2_kernel(int* __restrict__ blockSums, int nb)
{
    __shared__ int s[256];
    const int t = threadIdx.x;
    const int v = (t < nb) ? blockSums[t] : 0;
    s[t] = v;
    __syncthreads();
    int incl = v;
    for (int off = 1; off < 256; off <<= 1) {
        const int u = (t >= off) ? s[t - off] : 0;
        __syncthreads();
        incl += u;
        s[t] = incl;
        __syncthreads();
    }
    if (t < nb) blockSums[t] = incl - v;
}

__global__ __launch_bounds__(256) void scan3_kernel(
    const int* __restrict__ deg, const int* __restrict__ blockSums,
    int* __restrict__ rowPtr, int* __restrict__ cursor, int N, int twoE)
{
    const int i = blockIdx.x * blockDim.x + threadIdx.x;
    if (i == 0) rowPtr[N] = twoE;
    if (i >= N) return;
    const int v = deg[i] + blockSums[i / SCAN_CHUNK];
    rowPtr[i] = v;
    cursor[i] = v;
}

// fill: also computes e = sigmoid(leakyrelu(s[src]+d[dst])) per edge.
// Record: {row = rel*N + dst, e bits}
__global__ __launch_bounds__(256) void fill_kernel(
    const int* __restrict__ adj_pos, const int* __restrict__ adj_neg,
    const float* __restrict__ sd,
    int* __restrict__ cursor, uint2* __restrict__ edges, int N, int E)
{
    const int idx = blockIdx.x * blockDim.x + threadIdx.x;
    if (idx >= 2 * E) return;
    const int rel = (idx >= E) ? 1 : 0;
    const int e = rel ? idx - E : idx;
    const int* __restrict__ adj = rel ? adj_neg : adj_pos;
    const int src = adj[e];
    const int dst = adj[E + e];
    const float* __restrict__ s = sd + (size_t)rel * 2 * N;
    const float* __restrict__ d = s + N;
    float z = s[src] + d[dst];
    z = z > 0.f ? z : ALPHA * z;
    const float ev = 1.f / (1.f + __expf(-z));
    const int pos = atomicAdd(&cursor[src], 1);
    uint2 rec;
    rec.x = (unsigned int)(rel * N + dst);
    rec.y = __float_as_uint(ev);
    edges[pos] = rec;
}

// ---------------------------------------------------------------------------
// Gather: one wave per node; 4-deep unrolled so 4 h-row gathers are in flight.
// ---------------------------------------------------------------------------
__global__ __launch_bounds__(256) void gather_kernel(
    const int* __restrict__ rowPtr, const uint2* __restrict__ edges,
    const unsigned short* __restrict__ h,
    const float* __restrict__ bias, float* __restrict__ out, int N)
{
    const long long gw = ((long long)blockIdx.x * blockDim.x + threadIdx.x) >> 6;
    const int lane = threadIdx.x & 63;
    if (gw >= N) return;
    const int n = (int)gw;

    const int beg = rowPtr[n];
    const int end = rowPtr[n + 1];

    float ax = 0.f, ay = 0.f, rs = 0.f;
    int j = beg;
    for (; j + 4 <= end; j += 4) {
        const uint2 r0 = edges[j + 0];
        const uint2 r1 = edges[j + 1];
        const uint2 r2 = edges[j + 2];
        const uint2 r3 = edges[j + 3];
        const unsigned int h0 = *reinterpret_cast<const unsigned int*>(
            &h[(size_t)r0.x * 128 + lane * 2]);
        const unsigned int h1 = *reinterpret_cast<const unsigned int*>(
            &h[(size_t)r1.x * 128 + lane * 2]);
        const unsigned int h2 = *reinterpret_cast<const unsigned int*>(
            &h[(size_t)r2.x * 128 + lane * 2]);
        const unsigned int h3 = *reinterpret_cast<const unsigned int*>(
            &h[(size_t)r3.x * 128 + lane * 2]);
        const float e0 = __uint_as_float(r0.y);
        const float e1 = __uint_as_float(r1.y);
        const float e2 = __uint_as_float(r2.y);
        const float e3 = __uint_as_float(r3.y);
        rs += (e0 + e1) + (e2 + e3);
        ax += e0 * bflo(h0) + e1 * bflo(h1) + e2 * bflo(h2) + e3 * bflo(h3);
        ay += e0 * bfhi(h0) + e1 * bfhi(h1) + e2 * bfhi(h2) + e3 * bfhi(h3);
    }
    for (; j < end; ++j) {
        const uint2 r = edges[j];
        const unsigned int hv = *reinterpret_cast<const unsigned int*>(
            &h[(size_t)r.x * 128 + lane * 2]);
        const float e = __uint_as_float(r.y);
        rs += e;
        ax += e * bflo(hv);
        ay += e * bfhi(hv);
    }
    const float inv = 1.f / (rs + EPSV);
    const float2 bv = *reinterpret_cast<const float2*>(&bias[lane * 2]);
    float2 o;
    o.x = ax * inv + bv.x;
    o.y = ay * inv + bv.y;
    *reinterpret_cast<float2*>(&out[(size_t)n * 128 + lane * 2]) = o;
}

extern "C" void kernel_launch(void* const* d_in, const int* in_sizes, int n_in,
                              void* d_out, int out_size, void* d_ws, size_t ws_size,
                              hipStream_t stream) {
    const float* X      = (const float*)d_in[0];   // N x 256
    const float* ee     = (const float*)d_in[1];   // 2 x 128
    const float* Wr     = (const float*)d_in[2];   // 2 x 256 x 128
    const float* a      = (const float*)d_in[3];   // 1 x 256
    const float* bias   = (const float*)d_in[4];   // 1 x 128
    const int* adj_pos  = (const int*)d_in[5];     // 2 x E
    const int* adj_neg  = (const int*)d_in[6];     // 2 x E

    const int N = in_sizes[0] / 256;
    const int E = in_sizes[5] / 2;
    const int twoE = 2 * E;
    float* out = (float*)d_out;

    const int gemmBlocks = (N + 63) / 64;

    // workspace layout
    char* ws = (char*)d_ws;
    uint4* Bp = (uint4*)ws;
    char* p = ws + 32 * 256 * 16;                               // 128 KB
    unsigned short* h = (unsigned short*)p; p += (size_t)2 * N * 128 * 2; // 51.2 MB
    float* sd      = (float*)p;  p += (size_t)4 * N * 4;
    int* deg       = (int*)p;    p += (size_t)N * 4;
    int* rowPtr    = (int*)p;    p += (size_t)(N + 1) * 4;
    int* cursor    = (int*)p;    p += (size_t)N * 4;
    int* blockSums = (int*)p;    p += 256 * 4;
    p = (char*)(((uintptr_t)p + 15) & ~(uintptr_t)15);
    uint2* edges   = (uint2*)p;  p += (size_t)twoE * 8;         // 12.8 MB

    const int nb = (N + SCAN_CHUNK - 1) / SCAN_CHUNK;

    (void)hipMemsetAsync(deg, 0, (size_t)N * sizeof(int), stream);

    convB_kernel<<<(32 * 256 + 255) / 256, 256, 0, stream>>>(Wr, Bp);
    mfma_gemm_kernel<<<gemmBlocks, 256, 0, stream>>>(X, Bp, ee, a, h, sd, N);

    count_kernel<<<(twoE + 255) / 256, 256, 0, stream>>>(adj_pos, adj_neg, deg, E);
    scan1_kernel<<<nb, 256, 0, stream>>>(deg, blockSums, N);
    scan2_kernel<<<1, 256, 0, stream>>>(blockSums, nb);
    scan3_kernel<<<(N + 255) / 256, 256, 0, stream>>>(deg, blockSums, rowPtr, cursor, N, twoE);
    fill_kernel<<<(twoE + 255) / 256, 256, 0, stream>>>(
        adj_pos, adj_neg, sd, cursor, edges, N, E);

    gather_kernel<<<(int)(((long long)N * 64 + 255) / 256), 256, 0, stream>>>(
        rowPtr, edges, h, bias, out, N);
}